// Round 6
// baseline (4893.254 us; speedup 1.0000x reference)
//
#include <hip/hip_runtime.h>
#include <stdint.h>

#define N_POINTS  400000
#define WIDTH     64
#define M_SAMPLES 1000              // N_POINTS / 400
#define NBLK      128               // 1 wave per block -> no barriers, no LDS
#define NTHR      64
#define NTOT      (NBLK * NTHR)     // 8192 threads
#define PPT       49                // ceil(400000 / 8192)
#define NREC      NBLK              // one record per block(=wave)
#define ROWU64    (4 * NREC)        // 4 planes x 128 records = 512 u64 = 4 KB
// mailbox: 2 rows x 4 KB = 8 KB in d_ws, double-buffered by (i & 1)

#define LOADSLOT(p)     __hip_atomic_load((p), __ATOMIC_RELAXED, __HIP_MEMORY_SCOPE_AGENT)
#define STORESLOT(p, v) __hip_atomic_store((p), (v), __ATOMIC_RELAXED, __HIP_MEMORY_SCOPE_AGENT)

__device__ inline unsigned long long shfl_xor_u64(unsigned long long x, int m) {
    unsigned int lo = (unsigned int)x;
    unsigned int hi = (unsigned int)(x >> 32);
    lo = __shfl_xor(lo, m, 64);
    hi = __shfl_xor(hi, m, 64);
    return ((unsigned long long)hi << 32) | lo;
}

__global__ void fps_init(unsigned long long* slot, int* out) {
    int t = blockIdx.x * blockDim.x + threadIdx.x;
    if (t < 2 * ROWU64) slot[t] = 0ull;   // tag 0 != any live tag (i >= 1)
    if (t == 0) out[0] = 0;               // seed index
}

__global__ __launch_bounds__(NTHR)
void fps_main(const float* __restrict__ feats, int* __restrict__ out,
              unsigned long long* __restrict__ slot)
{
    const int lane = threadIdx.x;        // block == wave
    const int bid  = blockIdx.x;
    const int gid  = bid * NTHR + lane;

    // Register-resident points + running min squared distance
    float px[PPT], py[PPT], pz[PPT], dd[PPT];
#pragma unroll
    for (int k = 0; k < PPT; k++) {
        int j = gid + k * NTOT;
        if (j < N_POINTS) {
            px[k] = feats[(size_t)j * WIDTH + 0];
            py[k] = feats[(size_t)j * WIDTH + 1];
            pz[k] = feats[(size_t)j * WIDTH + 2];
        } else {
            px[k] = 0.f; py[k] = 0.f; pz[k] = 0.f;
        }
        dd[k] = 1e10f;          // matches jnp.full(..., 1e10, f32)
    }

    // Seed pivot = point 0; feats is never touched again after this
    float qx = feats[0], qy = feats[1], qz = feats[2];

    for (int i = 1; i < M_SAMPLES; i++) {
        const unsigned long long tag = (unsigned long long)i;   // UNIQUE per round

        // ---- distance update + per-thread argmax (strict > keeps lowest j) ----
        float bnd, bx, by, bz; int bj;
        {
            float dx = __fsub_rn(px[0], qx);
            float dy = __fsub_rn(py[0], qy);
            float dz = __fsub_rn(pz[0], qz);
            float d  = __fadd_rn(__fadd_rn(__fmul_rn(dx, dx), __fmul_rn(dy, dy)),
                                 __fmul_rn(dz, dz));
            float nd = fminf(dd[0], d);
            dd[0] = nd;
            bnd = nd; bj = gid; bx = px[0]; by = py[0]; bz = pz[0];
        }
#pragma unroll
        for (int k = 1; k < PPT; k++) {
            int j = gid + k * NTOT;
            float dx = __fsub_rn(px[k], qx);
            float dy = __fsub_rn(py[k], qy);
            float dz = __fsub_rn(pz[k], qz);
            float d  = __fadd_rn(__fadd_rn(__fmul_rn(dx, dx), __fmul_rn(dy, dy)),
                                 __fmul_rn(dz, dz));
            float nd = fminf(dd[k], d);
            dd[k] = nd;
            bool valid = (k < PPT - 1) || (j < N_POINTS);  // runtime only for k=48
            if (valid && nd > bnd) { bnd = nd; bj = j; bx = px[k]; by = py[k]; bz = pz[k]; }
        }

        // key: [63:32]=dist bits (nonneg -> monotone), [28:10]=(N-j), [9:0]=tag(i)
        // max key = max dist; ties -> lowest index (argmax first-max semantics)
        unsigned long long key =
            ((unsigned long long)__float_as_uint(bnd) << 32) |
            ((unsigned long long)(unsigned)(N_POINTS - bj) << 10) | tag;

        // ---- wave butterfly carrying payload; all lanes end with wave winner ----
#pragma unroll
        for (int m = 32; m > 0; m >>= 1) {
            unsigned long long ok = shfl_xor_u64(key, m);
            float ox = __shfl_xor(bx, m, 64);
            float oy = __shfl_xor(by, m, 64);
            float oz = __shfl_xor(bz, m, 64);
            if (ok > key) { key = ok; bx = ox; by = oy; bz = oz; }
        }

        // ---- publish immediately: lanes 0-3 store planes key,x,y,z (1 instr) ----
        unsigned long long* row = slot + (size_t)(i & 1) * ROWU64;
        if (lane < 4) {
            float c = (lane == 1) ? bx : (lane == 2) ? by : bz;
            unsigned long long cv = ((unsigned long long)__float_as_uint(c) << 32) | tag;
            unsigned long long myval = (lane == 0) ? key : cv;
            STORESLOT(row + lane * NREC + bid, myval);
        }

        // ---- poll: lane l owns records l and l+64; 8 lane-contiguous loads ----
        unsigned long long k0, x0, y0, z0, k1, x1, y1, z1;
        for (;;) {
            k0 = LOADSLOT(row + lane);
            k1 = LOADSLOT(row + lane + 64);
            x0 = LOADSLOT(row + NREC + lane);
            x1 = LOADSLOT(row + NREC + lane + 64);
            y0 = LOADSLOT(row + 2 * NREC + lane);
            y1 = LOADSLOT(row + 2 * NREC + lane + 64);
            z0 = LOADSLOT(row + 3 * NREC + lane);
            z1 = LOADSLOT(row + 3 * NREC + lane + 64);
            bool ok = ((k0 & 1023u) == tag) & ((k1 & 1023u) == tag)
                    & ((x0 & 1023u) == tag) & ((x1 & 1023u) == tag)
                    & ((y0 & 1023u) == tag) & ((y1 & 1023u) == tag)
                    & ((z0 & 1023u) == tag) & ((z1 & 1023u) == tag);
            if (ok) break;   // divergent; lanes reconverge when all exit
        }

        // ---- reduce 2 local records, then payload butterfly -> global winner ----
        unsigned long long K = k0; unsigned long long Xv = x0, Yv = y0, Zv = z0;
        if (k1 > K) { K = k1; Xv = x1; Yv = y1; Zv = z1; }
        float X = __uint_as_float((unsigned)(Xv >> 32));
        float Y = __uint_as_float((unsigned)(Yv >> 32));
        float Z = __uint_as_float((unsigned)(Zv >> 32));
#pragma unroll
        for (int m = 32; m > 0; m >>= 1) {
            unsigned long long oK = shfl_xor_u64(K, m);
            float oX = __shfl_xor(X, m, 64);
            float oY = __shfl_xor(Y, m, 64);
            float oZ = __shfl_xor(Z, m, 64);
            if (oK > K) { K = oK; X = oX; Y = oY; Z = oZ; }
        }

        // Next pivot comes straight out of registers — no memory on the path.
        qx = X; qy = Y; qz = Z;
        if (bid == 0 && lane == 0)
            out[i] = (int)(N_POINTS - (unsigned)((K >> 10) & 0x7FFFFu));
    }
}

extern "C" void kernel_launch(void* const* d_in, const int* in_sizes, int n_in,
                              void* d_out, int out_size, void* d_ws, size_t ws_size,
                              hipStream_t stream) {
    const float* feats = (const float*)d_in[0];
    int* out = (int*)d_out;
    unsigned long long* slot = (unsigned long long*)d_ws;  // 8 KB mailbox

    fps_init<<<(2 * ROWU64 + 255) / 256, 256, 0, stream>>>(slot, out);
    // 128 blocks x 64 thr: 1 single-wave block per CU on 256 CUs -> co-resident
    fps_main<<<NBLK, NTHR, 0, stream>>>(feats, out, slot);
}

// Round 7
// 4294.046 us; speedup vs baseline: 1.1395x; 1.1395x over previous
//
#include <hip/hip_runtime.h>
#include <stdint.h>

#define N_POINTS  400000
#define WIDTH     64
#define M_SAMPLES 1000              // N_POINTS / 400
#define NBLK      64
#define NTHR      256
#define NW        (NTHR / 64)       // 4 waves per block
#define NTOT      (NBLK * NTHR)     // 16384 threads
#define PPT       25                // ceil(400000 / 16384)
#define NREC      NBLK              // one record per block
#define ROWU64    (4 * NREC)        // 4 planes (key,x,y,z) x 64 records = 2 KB
// mailbox: 2 rows x 2 KB = 4 KB in d_ws, double-buffered by (i & 1)

typedef unsigned long long u64;

#define GLOAD(p)     __hip_atomic_load((p), __ATOMIC_RELAXED, __HIP_MEMORY_SCOPE_AGENT)
#define GSTORE(p, v) __hip_atomic_store((p), (v), __ATOMIC_RELAXED, __HIP_MEMORY_SCOPE_AGENT)
#define LLOAD(p)     __hip_atomic_load((p), __ATOMIC_RELAXED, __HIP_MEMORY_SCOPE_WORKGROUP)
#define LSTORE(p, v) __hip_atomic_store((p), (v), __ATOMIC_RELAXED, __HIP_MEMORY_SCOPE_WORKGROUP)

__device__ inline u64 shfl_xor_u64(u64 x, int m) {
    unsigned int lo = (unsigned int)x;
    unsigned int hi = (unsigned int)(x >> 32);
    lo = __shfl_xor(lo, m, 64);
    hi = __shfl_xor(hi, m, 64);
    return ((u64)hi << 32) | lo;
}

__global__ void fps_init(u64* slot, int* out) {
    int t = blockIdx.x * blockDim.x + threadIdx.x;
    if (t < 2 * ROWU64) slot[t] = 0ull;   // tag 0 != any live tag (i >= 1)
    if (t == 0) out[0] = 0;               // seed index
}

__global__ __launch_bounds__(NTHR)
void fps_main(const float* __restrict__ feats, int* __restrict__ out,
              u64* __restrict__ slot)
{
    const int tid  = threadIdx.x;
    const int bid  = blockIdx.x;
    const int lane = tid & 63;
    const int wid  = tid >> 6;
    const int gid  = bid * NTHR + tid;

    // Register-resident points + running min squared distance
    float px[PPT], py[PPT], pz[PPT], dd[PPT];
#pragma unroll
    for (int k = 0; k < PPT; k++) {
        int j = gid + k * NTOT;
        if (j < N_POINTS) {
            px[k] = feats[(size_t)j * WIDTH + 0];
            py[k] = feats[(size_t)j * WIDTH + 1];
            pz[k] = feats[(size_t)j * WIDTH + 2];
        } else {
            px[k] = 0.f; py[k] = 0.f; pz[k] = 0.f;
        }
        dd[k] = 1e10f;          // matches jnp.full(..., 1e10, f32)
    }

    // LDS mailboxes (tag-validated spins; NO __syncthreads in the loop)
    __shared__ u64 lds_cand[NW * 4];   // [wave][plane] key,x,y,z (waves 1-3 use)
    __shared__ u64 lds_win[4];         // winner broadcast, 4 planes

    // Seed pivot = point 0; feats never touched again after this
    float qx = feats[0], qy = feats[1], qz = feats[2];

    for (int i = 1; i < M_SAMPLES; i++) {
        const u64 tag = (u64)i;        // UNIQUE 10-bit tag -> no ABA anywhere

        // ---- distance update + per-thread argmax (strict > keeps lowest j) ----
        float bnd, bx, by, bz; int bj;
        {
            float dx = __fsub_rn(px[0], qx);
            float dy = __fsub_rn(py[0], qy);
            float dz = __fsub_rn(pz[0], qz);
            float d  = __fadd_rn(__fadd_rn(__fmul_rn(dx, dx), __fmul_rn(dy, dy)),
                                 __fmul_rn(dz, dz));
            float nd = fminf(dd[0], d);
            dd[0] = nd;
            bnd = nd; bj = gid; bx = px[0]; by = py[0]; bz = pz[0];
        }
#pragma unroll
        for (int k = 1; k < PPT; k++) {
            int j = gid + k * NTOT;
            float dx = __fsub_rn(px[k], qx);
            float dy = __fsub_rn(py[k], qy);
            float dz = __fsub_rn(pz[k], qz);
            float d  = __fadd_rn(__fadd_rn(__fmul_rn(dx, dx), __fmul_rn(dy, dy)),
                                 __fmul_rn(dz, dz));
            float nd = fminf(dd[k], d);
            dd[k] = nd;
            bool valid = (k < PPT - 1) || (j < N_POINTS);  // runtime only for k=24
            if (valid && nd > bnd) { bnd = nd; bj = j; bx = px[k]; by = py[k]; bz = pz[k]; }
        }

        // key: [63:32]=dist bits (nonneg -> monotone), [28:10]=(N-j), [9:0]=tag
        u64 key = ((u64)__float_as_uint(bnd) << 32) |
                  ((u64)(unsigned)(N_POINTS - bj) << 10) | tag;

        // ---- wave butterfly carrying payload ----
#pragma unroll
        for (int m = 32; m > 0; m >>= 1) {
            u64 ok = shfl_xor_u64(key, m);
            float ox = __shfl_xor(bx, m, 64);
            float oy = __shfl_xor(by, m, 64);
            float oz = __shfl_xor(bz, m, 64);
            if (ok > key) { key = ok; bx = ox; by = oy; bz = oz; }
        }

        if (wid != 0) {
            // ---- waves 1-3: publish candidate to LDS, then spin on winner ----
            if (lane < 4) {
                float c = (lane == 1) ? bx : (lane == 2) ? by : bz;
                u64 cv = ((u64)__float_as_uint(c) << 32) | tag;
                LSTORE(&lds_cand[wid * 4 + lane], (lane == 0) ? key : cv);
            }
            u64 w1, w2, w3;   // winner coord planes (uniform LDS reads)
            for (;;) {
                u64 w0 = LLOAD(&lds_win[0]);
                w1 = LLOAD(&lds_win[1]);
                w2 = LLOAD(&lds_win[2]);
                w3 = LLOAD(&lds_win[3]);
                if (((w0 & 1023u) == tag) & ((w1 & 1023u) == tag) &
                    ((w2 & 1023u) == tag) & ((w3 & 1023u) == tag)) break;
            }
            qx = __uint_as_float((unsigned)(w1 >> 32));
            qy = __uint_as_float((unsigned)(w2 >> 32));
            qz = __uint_as_float((unsigned)(w3 >> 32));
        } else {
            // ---- wave 0: gather waves 1-3 from LDS (spin), block-reduce ----
            u64 K = key; float X = bx, Y = by, Z = bz;
            u64 ck = 0, cx = 0, cy = 0, cz = 0;
            for (;;) {
                bool ok = true;
                if (lane >= 1 && lane < 4) {
                    ck = LLOAD(&lds_cand[lane * 4 + 0]);
                    cx = LLOAD(&lds_cand[lane * 4 + 1]);
                    cy = LLOAD(&lds_cand[lane * 4 + 2]);
                    cz = LLOAD(&lds_cand[lane * 4 + 3]);
                    ok = ((ck & 1023u) == tag) & ((cx & 1023u) == tag) &
                         ((cy & 1023u) == tag) & ((cz & 1023u) == tag);
                }
                if (__all(ok)) break;
            }
            if (lane >= 1 && lane < 4) {
                K = ck;
                X = __uint_as_float((unsigned)(cx >> 32));
                Y = __uint_as_float((unsigned)(cy >> 32));
                Z = __uint_as_float((unsigned)(cz >> 32));
            }
            // quad butterfly (xor 1,2): lanes 0-3 all end with the block winner
#pragma unroll
            for (int m = 1; m <= 2; m <<= 1) {
                u64 oK = shfl_xor_u64(K, m);
                float oX = __shfl_xor(X, m, 64);
                float oY = __shfl_xor(Y, m, 64);
                float oZ = __shfl_xor(Z, m, 64);
                if (oK > K) { K = oK; X = oX; Y = oY; Z = oZ; }
            }

            // ---- publish block record IMMEDIATELY (lanes 0-3, one instr) ----
            u64* row = slot + (size_t)(i & 1) * ROWU64;
            if (lane < 4) {
                float c = (lane == 1) ? X : (lane == 2) ? Y : Z;
                u64 cv = ((u64)__float_as_uint(c) << 32) | tag;
                GSTORE(row + lane * NREC + bid, (lane == 0) ? K : cv);
            }

            // ---- poll: lane l owns block-record l; 4 lane-contiguous loads ----
            u64 pk, pxv, pyv, pzv;
            for (;;) {
                pk  = GLOAD(row + lane);
                pxv = GLOAD(row + NREC + lane);
                pyv = GLOAD(row + 2 * NREC + lane);
                pzv = GLOAD(row + 3 * NREC + lane);
                bool ok = ((pk  & 1023u) == tag) & ((pxv & 1023u) == tag) &
                          ((pyv & 1023u) == tag) & ((pzv & 1023u) == tag);
                if (__all(ok)) break;
            }
            K = pk;
            X = __uint_as_float((unsigned)(pxv >> 32));
            Y = __uint_as_float((unsigned)(pyv >> 32));
            Z = __uint_as_float((unsigned)(pzv >> 32));
#pragma unroll
            for (int m = 32; m > 0; m >>= 1) {
                u64 oK = shfl_xor_u64(K, m);
                float oX = __shfl_xor(X, m, 64);
                float oY = __shfl_xor(Y, m, 64);
                float oZ = __shfl_xor(Z, m, 64);
                if (oK > K) { K = oK; X = oX; Y = oY; Z = oZ; }
            }

            // ---- broadcast winner to waves 1-3 via LDS (tagged) ----
            if (lane < 4) {
                float c = (lane == 1) ? X : (lane == 2) ? Y : Z;
                u64 cv = ((u64)__float_as_uint(c) << 32) | tag;
                LSTORE(&lds_win[lane], (lane == 0) ? (K | 0) : cv);
            }
            qx = X; qy = Y; qz = Z;
            if (bid == 0 && lane == 0)
                out[i] = (int)(N_POINTS - (unsigned)((K >> 10) & 0x7FFFFu));
        }
    }
}

extern "C" void kernel_launch(void* const* d_in, const int* in_sizes, int n_in,
                              void* d_out, int out_size, void* d_ws, size_t ws_size,
                              hipStream_t stream) {
    const float* feats = (const float*)d_in[0];
    int* out = (int*)d_out;
    u64* slot = (u64*)d_ws;   // 4 KB mailbox

    fps_init<<<2, 256, 0, stream>>>(slot, out);
    // 64 blocks x 256 thr: 1 block/CU -> co-residency guaranteed
    fps_main<<<NBLK, NTHR, 0, stream>>>(feats, out, slot);
}

// Round 8
// 3661.192 us; speedup vs baseline: 1.3365x; 1.1729x over previous
//
#include <hip/hip_runtime.h>
#include <stdint.h>

#define N_POINTS  400000
#define WIDTH     64
#define M_SAMPLES 1000              // N_POINTS / 400
#define NBLK      64
#define NTHR      256
#define NW        (NTHR / 64)       // 4 waves per block
#define NREC      (NBLK * NW)       // 256 per-wave records per round
#define NTOT      (NBLK * NTHR)     // 16384 threads
#define PPT       25                // ceil(400000 / 16384)
// mailbox: 2 rows x 256 u64 = 4 KB in d_ws, double-buffered by (i & 1).
// Hot + tag-validated -> permanently MALL-resident, no HBM misses in poll.

typedef unsigned long long u64;

#define GLOAD(p)     __hip_atomic_load((p), __ATOMIC_RELAXED, __HIP_MEMORY_SCOPE_AGENT)
#define GSTORE(p, v) __hip_atomic_store((p), (v), __ATOMIC_RELAXED, __HIP_MEMORY_SCOPE_AGENT)

__device__ inline u64 shfl_xor_u64(u64 x, int m) {
    unsigned int lo = (unsigned int)x;
    unsigned int hi = (unsigned int)(x >> 32);
    lo = __shfl_xor(lo, m, 64);
    hi = __shfl_xor(hi, m, 64);
    return ((u64)hi << 32) | lo;
}

__global__ void fps_init(u64* slot, int* out) {
    int t = blockIdx.x * blockDim.x + threadIdx.x;
    if (t < 2 * NREC) slot[t] = 0ull;   // tag 0 != any live tag (i >= 1)
    if (t == 0) out[0] = 0;             // seed index
}

__global__ __launch_bounds__(NTHR)
void fps_main(const float* __restrict__ feats, int* __restrict__ out,
              u64* __restrict__ slot)
{
    const int tid  = threadIdx.x;
    const int bid  = blockIdx.x;
    const int lane = tid & 63;
    const int wid  = tid >> 6;
    const int gid  = bid * NTHR + tid;
    const int rec  = wid * NBLK + bid;   // transposed: poll is lane-contiguous

    // Register-resident points + running min squared distance
    float px[PPT], py[PPT], pz[PPT], dd[PPT];
#pragma unroll
    for (int k = 0; k < PPT; k++) {
        int j = gid + k * NTOT;
        if (j < N_POINTS) {
            px[k] = feats[(size_t)j * WIDTH + 0];
            py[k] = feats[(size_t)j * WIDTH + 1];
            pz[k] = feats[(size_t)j * WIDTH + 2];
        } else {
            px[k] = 0.f; py[k] = 0.f; pz[k] = 0.f;
        }
        dd[k] = 1e10f;          // matches jnp.full(..., 1e10, f32)
    }

    __shared__ u64 s_key;

    int last = 0;
    for (int i = 1; i < M_SAMPLES; i++) {
        const u64 tag = (u64)i;          // unique 10-bit tag per round

        // Pivot coords (wave-uniform address; one transaction per wave)
        float qx = feats[(size_t)last * WIDTH + 0];
        float qy = feats[(size_t)last * WIDTH + 1];
        float qz = feats[(size_t)last * WIDTH + 2];

        // ---- distance update + per-thread argmax (strict > keeps lowest j) ----
        float bnd; int bj;
        {
            float dx = __fsub_rn(px[0], qx);
            float dy = __fsub_rn(py[0], qy);
            float dz = __fsub_rn(pz[0], qz);
            float d  = __fadd_rn(__fadd_rn(__fmul_rn(dx, dx), __fmul_rn(dy, dy)),
                                 __fmul_rn(dz, dz));
            float nd = fminf(dd[0], d);
            dd[0] = nd;
            bnd = nd; bj = gid;
        }
#pragma unroll
        for (int k = 1; k < PPT; k++) {
            int j = gid + k * NTOT;
            float dx = __fsub_rn(px[k], qx);
            float dy = __fsub_rn(py[k], qy);
            float dz = __fsub_rn(pz[k], qz);
            float d  = __fadd_rn(__fadd_rn(__fmul_rn(dx, dx), __fmul_rn(dy, dy)),
                                 __fmul_rn(dz, dz));
            float nd = fminf(dd[k], d);
            dd[k] = nd;
            bool valid = (k < PPT - 1) || (j < N_POINTS);  // runtime only for k=24
            if (valid && nd > bnd) { bnd = nd; bj = j; }
        }

        // key: [63:32]=dist bits (nonneg -> monotone), [28:10]=(N-j) 19b, [9:0]=tag
        // max key = max dist; ties -> lowest index (argmax first-max semantics)
        u64 key = ((u64)__float_as_uint(bnd) << 32) |
                  ((u64)(unsigned)(N_POINTS - bj) << 10) | tag;

        // ---- wave butterfly; lane 0 ends with the wave winner ----
#pragma unroll
        for (int m = 32; m > 0; m >>= 1) {
            u64 o = shfl_xor_u64(key, m);
            if (o > key) key = o;
        }

        // ---- per-WAVE immediate store: ungated, straight to the fabric ----
        u64* row = slot + (size_t)(i & 1) * NREC;
        if (lane == 0) GSTORE(row + rec, key);

        if (wid == 0) {
            // ---- sticky poll: lane l owns recs {l,l+64,l+128,l+192};
            //      each load is lane-contiguous 512 B (8 sectors, not 32) ----
            u64 k0 = 0, k1 = 0, k2 = 0, k3 = 0;
            for (;;) {
                if ((k0 & 1023u) != tag) k0 = GLOAD(row + lane);
                if ((k1 & 1023u) != tag) k1 = GLOAD(row + lane + 64);
                if ((k2 & 1023u) != tag) k2 = GLOAD(row + lane + 128);
                if ((k3 & 1023u) != tag) k3 = GLOAD(row + lane + 192);
                bool ok = ((k0 & 1023u) == tag) & ((k1 & 1023u) == tag) &
                          ((k2 & 1023u) == tag) & ((k3 & 1023u) == tag);
                if (ok) break;   // divergent; lanes reconverge when all exit
            }

            // ---- 4-way local max, then butterfly -> global winner ----
            u64 K = k0;
            if (k1 > K) K = k1;
            if (k2 > K) K = k2;
            if (k3 > K) K = k3;
#pragma unroll
            for (int m = 32; m > 0; m >>= 1) {
                u64 o = shfl_xor_u64(K, m);
                if (o > K) K = o;
            }
            if (lane == 0) {
                s_key = K;
                if (bid == 0)
                    out[i] = (int)(N_POINTS - (unsigned)((K >> 10) & 0x7FFFFu));
            }
        }
        // Single barrier: waves 1-3 arrive right after their store;
        // wave 0 releases it as soon as s_key is written.
        __syncthreads();
        last = (int)(N_POINTS - (unsigned)((s_key >> 10) & 0x7FFFFu));
    }
}

extern "C" void kernel_launch(void* const* d_in, const int* in_sizes, int n_in,
                              void* d_out, int out_size, void* d_ws, size_t ws_size,
                              hipStream_t stream) {
    const float* feats = (const float*)d_in[0];
    int* out = (int*)d_out;
    u64* slot = (u64*)d_ws;   // 4 KB hot mailbox

    fps_init<<<2, 256, 0, stream>>>(slot, out);
    // 64 blocks x 256 thr: 1 block/CU -> co-residency guaranteed
    fps_main<<<NBLK, NTHR, 0, stream>>>(feats, out, slot);
}